// Round 7
// baseline (85.427 us; speedup 1.0000x reference)
//
#include <hip/hip_runtime.h>
#include <hip/hip_bf16.h>

#define NN 16384
#define DD 128
#define BM 128                 // rows per block (2 rowbands of 64)
#define BCOLS 4096             // cols per block (one col-quarter)
#define TCOLS 64               // cols per tile layer (4 waves x 16)
#define TILES 64               // BCOLS / TCOLS
#define NBLOCKS 512            // 128 rstrips x 4 col-quarters
#define SQRT_SCALE 4.5398159622f   // sqrt(log2(e)/0.07); dot of scaled vecs == exp2 arg

typedef __attribute__((ext_vector_type(8))) short bf16x8;
typedef __attribute__((ext_vector_type(4))) float f32x4;

// ---------------- Kernel 1: fp32 -> scaled bf16, swizzled layout ---------------
// 16B chunk c of row r stored at chunk position (c ^ (r&15)); a linear
// global->LDS copy then yields a bank-conflict-free slice for ds_read_b128.
__global__ void convert_swz(const float* __restrict__ x, ushort* __restrict__ xb) {
    int t = blockIdx.x * blockDim.x + threadIdx.x;   // one thread per 8-elem chunk
    int r = t >> 4;
    int c = t & 15;
    const float4* src = (const float4*)(x + (size_t)r * DD + c * 8);
    float4 f0 = src[0];
    float4 f1 = src[1];
    float vals[8] = {f0.x, f0.y, f0.z, f0.w, f1.x, f1.y, f1.z, f1.w};
    bf16x8 v;
#pragma unroll
    for (int i = 0; i < 8; ++i) {
        __hip_bfloat16 h = __float2bfloat16(vals[i] * SQRT_SCALE);
        v[i] = (short)__builtin_bit_cast(unsigned short, h);
    }
    int cs = c ^ (r & 15);
    *(bf16x8*)(xb + (size_t)r * DD + cs * 8) = v;
}

// ---------------- Kernel 2: BARRIER-FREE streaming X·X^T -> exp2 -> row sums ---
// Block = 128 rows x 4096 cols, 8 waves (2 rowbands x 4 colwaves), wave tile
// 64 rows x 16 cols. Each wave stages ITS OWN 16-col B-slice into a private
// 2x4KB LDS region (global_load_lds, counted per-wave vmcnt) -> no barriers
// anywhere in the main loop. Waves dephase freely, so exp/VALU epilogues of
// some waves overlap MFMA of others on the same SIMD. No atomics.
__global__ __launch_bounds__(512, 4) void gemm_exp_stream(const ushort* __restrict__ xb,
                                                          float* __restrict__ rowsumP) {
    __shared__ __align__(16) char lds[8][2][4096];   // [wave][buf][4KB slice]

    const int tid  = threadIdx.x;
    const int lane = tid & 63;
    const int wid  = tid >> 6;       // 0..7
    const int frow = lane & 15;
    const int kq   = lane >> 4;

    // XCD locality: 2 XCDs share one 1 MB B-slab (L2-resident).
    const int bid    = blockIdx.x;
    const int cq     = (bid & 7) >> 1;                 // 0..3
    const int rstrip = ((bid >> 3) << 1) | (bid & 1);  // 0..127, bijective
    const int rw = wid >> 2;         // 0..1 -> 64-row band
    const int cw = wid & 3;          // 0..3 -> 16-col slice within tile layer
    const int R0 = rstrip * BM;
    const int C0 = cq * BCOLS;

    char* myL = &lds[wid][0][0];     // this wave's private 8 KB

    // Stage this wave's 16-col slice of tile layer t into private buf (4 gll).
    auto stage = [&](int buf, int t) {
        const char* g = (const char*)(xb + (size_t)(C0 + t * TCOLS + cw * 16) * DD);
#pragma unroll
        for (int j = 0; j < 4; ++j) {
            __builtin_amdgcn_global_load_lds(
                (const __attribute__((address_space(1))) unsigned int*)(g + j * 1024 + lane * 16),
                (__attribute__((address_space(3))) unsigned int*)(myL + buf * 4096 + j * 1024),
                16, 0, 0);
        }
    };

    stage(0, 0);
    stage(1, 1);

    // ---- A fragments: 64 rows per wave, full K=128, in registers forever ----
    bf16x8 af[4][4];                 // [m][kk]
#pragma unroll
    for (int m = 0; m < 4; ++m)
#pragma unroll
        for (int kk = 0; kk < 4; ++kk) {
            int ra = R0 + rw * 64 + m * 16 + frow;   // ra & 15 == frow
            int slot = (kk * 4 + kq) ^ frow;
            af[m][kk] = *(const bf16x8*)(xb + (size_t)ra * DD + slot * 8);
        }

    // ---- per-kk LDS byte offsets within the private slice ----
    int roff[4];
#pragma unroll
    for (int kk = 0; kk < 4; ++kk)
        roff[kk] = frow * 256 + ((((kk << 2) + kq) ^ frow) << 4);

    // Drain prologue (af + tiles 0,1); from here on vmcnt counts only staging.
    asm volatile("s_waitcnt vmcnt(0)" ::: "memory");

    const f32x4 zacc = {0.f, 0.f, 0.f, 0.f};
    float rs[4][4] = {};

    for (int t = 0; t < TILES; ++t) {
        const int cur = t & 1;
        const char* Bb = myL + cur * 4096;

        f32x4 acc[4];
        __builtin_amdgcn_s_setprio(1);
#pragma unroll
        for (int kk = 0; kk < 4; ++kk) {
            bf16x8 bfr = *(const bf16x8*)(Bb + roff[kk]);
            if (kk == 0) {
#pragma unroll
                for (int m = 0; m < 4; ++m)
                    acc[m] = __builtin_amdgcn_mfma_f32_16x16x32_bf16(
                        af[m][0], bfr, zacc, 0, 0, 0);
            } else {
#pragma unroll
                for (int m = 0; m < 4; ++m)
                    acc[m] = __builtin_amdgcn_mfma_f32_16x16x32_bf16(
                        af[m][kk], bfr, acc[m], 0, 0, 0);
            }
        }
        __builtin_amdgcn_s_setprio(0);

        // bfr->MFMA deps guarantee all ds_reads of buf `cur` retired; safe to
        // overwrite it with tile t+2 now. (sched_barrier pins the order.)
        __builtin_amdgcn_sched_barrier(0);
        if (t + 2 < TILES) stage(cur, t + 2);

        // Register-only epilogue; acc is already the exp2 argument.
#pragma unroll
        for (int m = 0; m < 4; ++m)
#pragma unroll
            for (int j = 0; j < 4; ++j)
                rs[m][j] += __builtin_amdgcn_exp2f(acc[m][j]);

        // Per-wave wait: tile t+1's 4 loads done (t+2's stay in flight).
        if (t < TILES - 2)
            asm volatile("s_waitcnt vmcnt(4)" ::: "memory");
        else if (t == TILES - 2)
            asm volatile("s_waitcnt vmcnt(0)" ::: "memory");
    }

    // ---- cross-lane reduce over the 16 col-lanes ----
#pragma unroll
    for (int m = 0; m < 4; ++m)
#pragma unroll
        for (int j = 0; j < 4; ++j) {
            float s = rs[m][j];
            s += __shfl_xor(s, 1);
            s += __shfl_xor(s, 2);
            s += __shfl_xor(s, 4);
            s += __shfl_xor(s, 8);
            rs[m][j] = s;
        }

    // ---- each colwave writes its own partial slice: no combine, no sync ----
    if (frow == 0) {
        const int p = cq * 4 + cw;           // partial slot 0..15
        float* dst = rowsumP + (size_t)p * NN + R0 + rw * 64 + kq * 4;
#pragma unroll
        for (int m = 0; m < 4; ++m) {
            float4 v = {rs[m][0], rs[m][1], rs[m][2], rs[m][3]};
            *(float4*)(dst + m * 16) = v;    // row = R0+rw*64+m*16+kq*4+j
        }
    }
}

// ---------------- Kernel 3a: per-row log, 64-block partial sums ----------------
__global__ void finalize_part(const float* __restrict__ rowsumP,
                              float* __restrict__ partial) {
    const int tid = threadIdx.x;
    const int r = blockIdx.x * 256 + tid;
    float rsum = 0.f;
#pragma unroll
    for (int p = 0; p < 16; ++p)
        rsum += rowsumP[p * NN + r];
    float s = __builtin_amdgcn_logf(rsum) * 0.69314718056f;
#pragma unroll
    for (int o = 1; o < 64; o <<= 1)
        s += __shfl_xor(s, o);
    __shared__ float wsum[4];
    if ((tid & 63) == 0) wsum[tid >> 6] = s;
    __syncthreads();
    if (tid == 0)
        partial[blockIdx.x] = wsum[0] + wsum[1] + wsum[2] + wsum[3];
}

// ---------------- Kernel 3b: final sum -----------------------------------------
__global__ void finalize_sum(const float* __restrict__ partial, float* __restrict__ out) {
    float s = partial[threadIdx.x];   // 64 threads
#pragma unroll
    for (int o = 1; o < 64; o <<= 1)
        s += __shfl_xor(s, o);
    if (threadIdx.x == 0)
        out[0] = s * (1.0f / NN);
}

extern "C" void kernel_launch(void* const* d_in, const int* in_sizes, int n_in,
                              void* d_out, int out_size, void* d_ws, size_t ws_size,
                              hipStream_t stream) {
    const float* x = (const float*)d_in[0];
    float* out = (float*)d_out;

    ushort* xb     = (ushort*)d_ws;                                // 4 MB scaled bf16
    float* rowsumP = (float*)((char*)d_ws + (size_t)NN * DD * 2);  // 16 x 64 KB partials
    float* partial = rowsumP + 16 * NN;                            // 64 floats

    convert_swz<<<(NN * 16) / 256, 256, 0, stream>>>(x, xb);
    gemm_exp_stream<<<NBLOCKS, 512, 0, stream>>>(xb, rowsumP);
    finalize_part<<<64, 256, 0, stream>>>(rowsumP, partial);
    finalize_sum<<<1, 64, 0, stream>>>(partial, out);
}